// Round 12
// baseline (2321.316 us; speedup 1.0000x reference)
//
#include <hip/hip_runtime.h>

// FutureTrajDecoder: 3-layer GRU rollout, B=16384, ES=HS=64, T=128, NOUT=2.
// R12 = R8 (best, 448us) rescaled to 2 WGs/CU, after R9/R10/R11 showed the
// per-visit sync chain resists shortening: R8 is latency-bound (period
// 2100 cyc/visit vs ~500 busy; all pipes <35%) -> fill the dead issue slots
// with a SECOND independent WG per CU instead of shrinking the chain.
//  - 512 WGs x 768 thr; each WG owns 2 batch tiles (32 rows). Same total
//    work per CU per t; two rings interleave on the SIMDs.
//  - __launch_bounds__(768, 6): 6 waves/SIMD (24/CU), VGPR cap 85 (have 76).
//  - LDS 28.5 KB/WG -> 2 WGs fit with slack.
//  - s_sleep(1) poll throttle: first check eager, then 64-cyc naps — cuts
//    spin flood on LDS pipe + issue slots (R11: re-reads during spins added
//    1.5e7 bank conflicts; polls are pure overhead).
//  - out-proj after the h-write+flag-post (off the ring chain; safe R10 bit).
// Core structure identical to R8: per-(layer,tile) generation flags
// (producer: ds_write h, lgkm drain, lane0 ds_add; consumer: volatile spin),
// two-phase wait (h-wait -> h-loads -> h-MFMAs overlap x-wait), 12 waves =
// 3 layer-stages x 4 col-groups, emb folded into L0, weights=A operand so
// h-store is one ds_write_b64, fp32 carry in VGPRs, gate scales folded into
// weights, biases in MFMA C-init, MFMA 16x16x32 f16 fp32-accum, x-side
// MFMAs chained (R10: never split a C-chain).

#define ESZ   64
#define HSZ   64
#define TLEN  128
#define NOUTC 2
#define NT    2               // batch tiles per WG
#define LDW   72              // fp16 row stride (144 B)
#define TB    (16*LDW)
#define L2E   1.44269504f

typedef _Float16 half8 __attribute__((ext_vector_type(8)));
typedef _Float16 half4 __attribute__((ext_vector_type(4)));
typedef float    floatx4 __attribute__((ext_vector_type(4)));
typedef float    floatx2 __attribute__((ext_vector_type(2)));

#define MFMA(a, b, c) __builtin_amdgcn_mfma_f32_16x16x32_f16((a), (b), (c), 0, 0, 0)

__global__ __launch_bounds__(768, 6) void gru_pipe(
    const float* __restrict__ enc,     // (B, 64)
    const float* __restrict__ emb_w,   // (64, 64)
    const float* __restrict__ emb_b,   // (64,)
    const float* __restrict__ w_ih,    // (3, 192, 64)
    const float* __restrict__ w_hh,    // (3, 192, 64)
    const float* __restrict__ b_ih,    // (3, 192)
    const float* __restrict__ b_hh,    // (3, 192)
    const float* __restrict__ out_w,   // (2, 64)
    const float* __restrict__ out_b,   // (2,)
    float* __restrict__ out)           // (B, 128, 2)
{
    __shared__ _Float16 s_hl[3 * NT * 2 * TB];  // h_l fp16 [layer][tile][parity=t&1]
    __shared__ float    s_btmp[3 * 64];         // folded emb bias (fp32)
    __shared__ int      s_flag[3 * NT];         // [layer][tile] generation counters

    const int tid  = threadIdx.x;
    const int wave = tid >> 6, lane = tid & 63;
    const int l = wave >> 2, g = wave & 3;      // layer-stage 0..2, colgroup 0..3
    const int q = lane >> 4, c = lane & 15;
    const int u  = (g << 4) | c;                // weight row this lane loads
    const int u4 = (g << 4) | (q << 2);         // first hidden unit this lane OWNS
    const long wgbase = (long)blockIdx.x * (NT * 16);

    // ---- stage enc (= x(0) = h(-1)) into all layer buffers, parity 1 ----
    if (tid < 256) {
        const int row = tid >> 3, k0 = (tid & 7) << 3;   // 8 floats per thread
        const int j = row >> 4, rr = row & 15;
        const float* p = enc + (wgbase + row) * ESZ + k0;
        floatx4 s0 = *(const floatx4*)p;
        floatx4 s1 = *(const floatx4*)(p + 4);
        half8 v;
        #pragma unroll
        for (int x = 0; x < 4; ++x) { v[x] = (_Float16)s0[x]; v[4 + x] = (_Float16)s1[x]; }
        #pragma unroll
        for (int ly = 0; ly < 3; ++ly)
            *(half8*)&s_hl[((ly * NT + j) * 2 + 1) * TB + rr * LDW + k0] = v;
    }
    if (tid < 3 * NT) s_flag[tid] = 0;

    // ---- weight fragments (A-operand) ----
    auto ldw8s = [&](const float* p, float sc) {
        floatx4 a = *(const floatx4*)p, b = *(const floatx4*)(p + 4);
        half8 v;
        #pragma unroll
        for (int x = 0; x < 4; ++x) { v[x] = (_Float16)(a[x] * sc); v[4 + x] = (_Float16)(b[x] * sc); }
        return v;
    };
    half8 fR[4], fZ[4], fNi[2], fNh[2], fO[2];
    fO[0] = fO[1] = half8{};
    if (l == 0) {
        // ---- fold W' = W_ih0 @ W_e (fp32), b' = W_ih0 @ b_e ----
        const float* wi = w_ih;
        const float* wh = w_hh;
        floatx4 aR[4], aZ[4], aN[4];
        #pragma unroll
        for (int x = 0; x < 4; ++x) { aR[x] = {0,0,0,0}; aZ[x] = {0,0,0,0}; aN[x] = {0,0,0,0}; }
        float bR = 0.f, bZ = 0.f, bN = 0.f;
        for (int k4 = 0; k4 < 64; k4 += 4) {
            floatx4 wr4 = *(const floatx4*)(wi + (u) * 64 + k4);
            floatx4 wz4 = *(const floatx4*)(wi + (64 + u) * 64 + k4);
            floatx4 wn4 = *(const floatx4*)(wi + (128 + u) * 64 + k4);
            floatx4 be4 = *(const floatx4*)(emb_b + k4);
            #pragma unroll
            for (int kk = 0; kk < 4; ++kk) {
                const float* er = emb_w + (k4 + kk) * 64;
                floatx4 e0 = *(const floatx4*)(er + q * 8);
                floatx4 e1 = *(const floatx4*)(er + q * 8 + 4);
                floatx4 e2 = *(const floatx4*)(er + 32 + q * 8);
                floatx4 e3 = *(const floatx4*)(er + 32 + q * 8 + 4);
                const float wr = wr4[kk], wz = wz4[kk], wn = wn4[kk];
                aR[0] += wr * e0; aR[1] += wr * e1; aR[2] += wr * e2; aR[3] += wr * e3;
                aZ[0] += wz * e0; aZ[1] += wz * e1; aZ[2] += wz * e2; aZ[3] += wz * e3;
                aN[0] += wn * e0; aN[1] += wn * e1; aN[2] += wn * e2; aN[3] += wn * e3;
                bR += wr * be4[kk]; bZ += wz * be4[kk]; bN += wn * be4[kk];
            }
        }
        #pragma unroll
        for (int x = 0; x < 4; ++x) {
            fR[0][x] = (_Float16)(-L2E * aR[0][x]);   fR[0][4 + x] = (_Float16)(-L2E * aR[1][x]);
            fR[1][x] = (_Float16)(-L2E * aR[2][x]);   fR[1][4 + x] = (_Float16)(-L2E * aR[3][x]);
            fZ[0][x] = (_Float16)(-L2E * aZ[0][x]);   fZ[0][4 + x] = (_Float16)(-L2E * aZ[1][x]);
            fZ[1][x] = (_Float16)(-L2E * aZ[2][x]);   fZ[1][4 + x] = (_Float16)(-L2E * aZ[3][x]);
            fNi[0][x] = (_Float16)(2*L2E * aN[0][x]); fNi[0][4 + x] = (_Float16)(2*L2E * aN[1][x]);
            fNi[1][x] = (_Float16)(2*L2E * aN[2][x]); fNi[1][4 + x] = (_Float16)(2*L2E * aN[3][x]);
        }
        fR[2]  = ldw8s(wh + (u) * 64 + q * 8, -L2E);        fR[3]  = ldw8s(wh + (u) * 64 + 32 + q * 8, -L2E);
        fZ[2]  = ldw8s(wh + (64 + u) * 64 + q * 8, -L2E);   fZ[3]  = ldw8s(wh + (64 + u) * 64 + 32 + q * 8, -L2E);
        fNh[0] = ldw8s(wh + (128 + u) * 64 + q * 8, 2*L2E); fNh[1] = ldw8s(wh + (128 + u) * 64 + 32 + q * 8, 2*L2E);
        if (q == 0) {                                // fold-bias per hidden unit u (q-invariant)
            s_btmp[u] = bR; s_btmp[64 + u] = bZ; s_btmp[128 + u] = bN;
        }
        const int oc = (c < NOUTC) ? c : 0;
        fO[0] = ldw8s(out_w + oc * 64 + q * 8, 1.f);
        fO[1] = ldw8s(out_w + oc * 64 + 32 + q * 8, 1.f);
    } else {
        const float* wi = w_ih + l * 3 * HSZ * ESZ;
        const float* wh = w_hh + l * 3 * HSZ * ESZ;
        fR[0]  = ldw8s(wi + (u) * 64 + q * 8, -L2E);        fR[1]  = ldw8s(wi + (u) * 64 + 32 + q * 8, -L2E);
        fR[2]  = ldw8s(wh + (u) * 64 + q * 8, -L2E);        fR[3]  = ldw8s(wh + (u) * 64 + 32 + q * 8, -L2E);
        fZ[0]  = ldw8s(wi + (64 + u) * 64 + q * 8, -L2E);   fZ[1]  = ldw8s(wi + (64 + u) * 64 + 32 + q * 8, -L2E);
        fZ[2]  = ldw8s(wh + (64 + u) * 64 + q * 8, -L2E);   fZ[3]  = ldw8s(wh + (64 + u) * 64 + 32 + q * 8, -L2E);
        fNi[0] = ldw8s(wi + (128 + u) * 64 + q * 8, 2*L2E); fNi[1] = ldw8s(wi + (128 + u) * 64 + 32 + q * 8, 2*L2E);
        fNh[0] = ldw8s(wh + (128 + u) * 64 + q * 8, 2*L2E); fNh[1] = ldw8s(wh + (128 + u) * 64 + 32 + q * 8, 2*L2E);
    }
    __syncthreads();                                 // staging + s_btmp + flags visible

    // ---- per-lane bias vectors (C-init), hidden units u4..u4+3 ----
    floatx4 bR4, bZ4, bNi4, bNh4;
    if (l == 0) {
        #pragma unroll
        for (int i = 0; i < 4; ++i) {
            bR4[i]  = -L2E * (s_btmp[u4 + i] + b_ih[u4 + i] + b_hh[u4 + i]);
            bZ4[i]  = -L2E * (s_btmp[64 + u4 + i] + b_ih[64 + u4 + i] + b_hh[64 + u4 + i]);
            bNi4[i] = 2.f * L2E * (s_btmp[128 + u4 + i] + b_ih[128 + u4 + i]);
            bNh4[i] = 2.f * L2E * b_hh[128 + u4 + i];
        }
    } else {
        const int b0 = l * 192;
        floatx4 bi0 = *(const floatx4*)(b_ih + b0 + u4),       bh0 = *(const floatx4*)(b_hh + b0 + u4);
        floatx4 bi1 = *(const floatx4*)(b_ih + b0 + 64 + u4),  bh1 = *(const floatx4*)(b_hh + b0 + 64 + u4);
        floatx4 bi2 = *(const floatx4*)(b_ih + b0 + 128 + u4), bh2 = *(const floatx4*)(b_hh + b0 + 128 + u4);
        #pragma unroll
        for (int i = 0; i < 4; ++i) {
            bR4[i]  = -L2E * (bi0[i] + bh0[i]);
            bZ4[i]  = -L2E * (bi1[i] + bh1[i]);
            bNi4[i] = 2.f * L2E * bi2[i];
            bNh4[i] = 2.f * L2E * bh2[i];
        }
    }
    const float ob0 = out_b[0], ob1 = out_b[1];

    // ---- fp32 h-carry in VGPRs: carr[j][i] = h[u4+i][batch c] of tile j ----
    floatx4 ca0 = *(const floatx4*)(enc + (wgbase + 0 * 16 + c) * 64 + u4);
    floatx4 ca1 = *(const floatx4*)(enc + (wgbase + 1 * 16 + c) * 64 + u4);

    const int ar = c * LDW + (q << 3);               // act-frag elem offset (B-operand)
    const int fh = l * NT, fx = ((l == 0) ? 2 : (l - 1)) * NT;

    auto iter = [&](const int j, floatx4& carr, const int t) {
        const int parh = (t + 1) & 1, parw = t & 1;
        // wait: h_l(t-1) complete (all 4 col-groups); eager first check, then nap
        {
            volatile const int* f = &s_flag[fh + j]; const int tg = 4 * t;
            int fa = *f;
            while (fa < tg) { __builtin_amdgcn_s_sleep(1); fa = *f; }
        }
        asm volatile("" ::: "memory");
        const _Float16* hb = s_hl + ((fh + j) * 2 + parh) * TB;
        half8 ah0 = *(const half8*)(hb + ar), ah1 = *(const half8*)(hb + ar + 32);
        floatx4 accr = bR4, accz = bZ4, accnh = bNh4;
        accr  = MFMA(fR[2], ah0, accr);   accr  = MFMA(fR[3], ah1, accr);
        accz  = MFMA(fZ[2], ah0, accz);   accz  = MFMA(fZ[3], ah1, accz);
        accnh = MFMA(fNh[0], ah0, accnh); accnh = MFMA(fNh[1], ah1, accnh);
        // wait: x ready (l=0: h2(t-1) gen t; l>=1: h_{l-1}(t) gen t+1)
        {
            volatile const int* f = &s_flag[fx + j];
            const int tg = (l == 0) ? 4 * t : 4 * t + 4;
            int fa = *f;
            while (fa < tg) { __builtin_amdgcn_s_sleep(1); fa = *f; }
        }
        asm volatile("" ::: "memory");
        const _Float16* xb = (l == 0) ? s_hl + ((2 * NT + j) * 2 + parh) * TB
                                      : s_hl + (((l - 1) * NT + j) * 2 + parw) * TB;
        half8 bx0 = *(const half8*)(xb + ar), bx1 = *(const half8*)(xb + ar + 32);
        // x-side MFMAs CHAINED into the same accumulators (R10 lesson)
        accr  = MFMA(fR[0], bx0, accr);   accr  = MFMA(fR[1], bx1, accr);
        accz  = MFMA(fZ[0], bx0, accz);   accz  = MFMA(fZ[1], bx1, accz);
        floatx4 accni = bNi4;
        accni = MFMA(fNi[0], bx0, accni); accni = MFMA(fNi[1], bx1, accni);
        half4 hv4; floatx4 hnew;
        #pragma unroll
        for (int i = 0; i < 4; ++i) {
            const float r  = __builtin_amdgcn_rcpf(1.f + __builtin_amdgcn_exp2f(accr[i]));
            const float z  = __builtin_amdgcn_rcpf(1.f + __builtin_amdgcn_exp2f(accz[i]));
            const float a  = accni[i] + r * accnh[i];
            const float n  = 1.f - 2.f * __builtin_amdgcn_rcpf(1.f + __builtin_amdgcn_exp2f(a));
            const float hv = n + z * (carr[i] - n);
            hnew[i] = hv; hv4[i] = (_Float16)hv;
        }
        *(half4*)(s_hl + ((fh + j) * 2 + parw) * TB + c * LDW + u4) = hv4;
        asm volatile("s_waitcnt lgkmcnt(0)" ::: "memory");   // write visible before post
        if (lane == 0) atomicAdd(&s_flag[fh + j], 1);
        carr = hnew;
        // out-proj AFTER the post — off the ring chain (bx still live)
        if (l == 0 && g == 0 && t >= 1) {            // out(t-1) = h2(t-1) @ out_w.T + out_b
            floatx4 oa = {ob0, ob1, 0.f, 0.f};
            oa = MFMA(fO[0], bx0, oa);
            oa = MFMA(fO[1], bx1, oa);
            if (q == 0) {
                const long row = wgbase + j * 16 + c;
                *(floatx2*)(out + (row * TLEN + (t - 1)) * NOUTC) = floatx2{oa[0], oa[1]};
            }
        }
    };

    for (int t = 0; t < TLEN; ++t) {
        iter(0, ca0, t); iter(1, ca1, t);
    }

    // ---- tail: out(127) from h2(127) ----
    if (l == 0 && g == 0) {
        #pragma unroll
        for (int j = 0; j < NT; ++j) {
            {
                volatile const int* f = &s_flag[2 * NT + j];
                int fa = *f;
                while (fa < 4 * TLEN) { __builtin_amdgcn_s_sleep(1); fa = *f; }
            }
            asm volatile("" ::: "memory");
            const _Float16* xb = s_hl + ((2 * NT + j) * 2 + 1) * TB;         // parity 127&1 = 1
            half8 bx0 = *(const half8*)(xb + ar), bx1 = *(const half8*)(xb + ar + 32);
            floatx4 oa = {ob0, ob1, 0.f, 0.f};
            oa = MFMA(fO[0], bx0, oa);
            oa = MFMA(fO[1], bx1, oa);
            if (q == 0) {
                const long row = wgbase + j * 16 + c;
                *(floatx2*)(out + (row * TLEN + 127) * NOUTC) = floatx2{oa[0], oa[1]};
            }
        }
    }
}

extern "C" void kernel_launch(void* const* d_in, const int* in_sizes, int n_in,
                              void* d_out, int out_size, void* d_ws, size_t ws_size,
                              hipStream_t stream) {
    (void)in_sizes; (void)n_in; (void)d_ws; (void)ws_size; (void)out_size;
    const int grid = 16384 / (NT * 16);   // 512 workgroups, 2 per CU
    gru_pipe<<<grid, 768, 0, stream>>>(
        (const float*)d_in[0],  // agentFutureTrajEnc
        (const float*)d_in[1],  // emb_w
        (const float*)d_in[2],  // emb_b
        (const float*)d_in[3],  // w_ih
        (const float*)d_in[4],  // w_hh
        (const float*)d_in[5],  // b_ih
        (const float*)d_in[6],  // b_hh
        (const float*)d_in[7],  // out_w
        (const float*)d_in[8],  // out_b
        (float*)d_out);
}

// Round 13
// 445.911 us; speedup vs baseline: 5.2058x; 5.2058x over previous
//
#include <hip/hip_runtime.h>

// FutureTrajDecoder: 3-layer GRU rollout, B=16384, ES=HS=64, T=128, NOUT=2.
// R13 = R8 (best, 448us) with 32-row tiles (NT=2), after R12's lesson:
// 2 WGs/CU is impossible (launch_bounds(768,6) VGPR cap 40 -> weight frags
// spilled to scratch -> 7GB HBM traffic, 2321us). The model that closes:
// R8 pays ~250 cyc of per-visit overhead (polls/addr/control) on ~176 cyc
// of gate math, 48 visits per CU per t; LDS pipe 65% and VALU 61% busy.
// Halve the visit count at constant work:
//  - each visit = 32 batch rows (2 subtiles) x 16 cols: 24 MFMAs, 8 gate
//    elems/lane, 8 b128 reads, 2 b64 writes -> 24 visits/CU/t.
//  - out-proj balanced: wave g serves tile g>>1 subtile g&1 (R8 had all 4
//    out-projs/t on L0/g0, a straggler gating every h0 flag).
//  - t-loop unrolled x2: parities and buffer offsets compile-time.
//  - __launch_bounds__(768,3): honest VGPR cap (~168), no spill cliff.
// Core sync identical to R8: per-(layer,tile) generation flags (producer:
// ds_write h, lgkm drain, lane0 ds_add; consumer: volatile eager spin),
// h-wait -> h-loads -> h-MFMAs overlap x-wait; 12 waves = 3 layer-stages x
// 4 col-groups; emb folded into L0; weights=A operand (h-store = b64);
// fp32 carry in VGPRs; gate scales folded into weights; biases in MFMA
// C-init; MFMA 16x16x32 f16 fp32-accum; x-MFMAs chained (R10 lesson).

#define ESZ   64
#define HSZ   64
#define TLEN  128
#define NOUTC 2
#define NT    2               // batch tiles per WG (32 rows each)
#define LDW   72              // fp16 row stride (144 B)
#define TB32  (32*LDW)        // one 32-row activation tile buffer
#define L2E   1.44269504f

typedef _Float16 half8 __attribute__((ext_vector_type(8)));
typedef _Float16 half4 __attribute__((ext_vector_type(4)));
typedef float    floatx4 __attribute__((ext_vector_type(4)));
typedef float    floatx2 __attribute__((ext_vector_type(2)));

#define MFMA(a, b, c) __builtin_amdgcn_mfma_f32_16x16x32_f16((a), (b), (c), 0, 0, 0)

__global__ __launch_bounds__(768, 3) void gru_pipe(
    const float* __restrict__ enc,     // (B, 64)
    const float* __restrict__ emb_w,   // (64, 64)
    const float* __restrict__ emb_b,   // (64,)
    const float* __restrict__ w_ih,    // (3, 192, 64)
    const float* __restrict__ w_hh,    // (3, 192, 64)
    const float* __restrict__ b_ih,    // (3, 192)
    const float* __restrict__ b_hh,    // (3, 192)
    const float* __restrict__ out_w,   // (2, 64)
    const float* __restrict__ out_b,   // (2,)
    float* __restrict__ out)           // (B, 128, 2)
{
    __shared__ _Float16 s_hl[3 * NT * 2 * TB32]; // h_l fp16 [layer][tile][parity]
    __shared__ float    s_btmp[3 * 64];          // folded emb bias (fp32)
    __shared__ int      s_flag[3 * NT];          // [layer][tile] generation counters

    const int tid  = threadIdx.x;
    const int wave = tid >> 6, lane = tid & 63;
    const int l = wave >> 2, g = wave & 3;      // layer-stage 0..2, colgroup 0..3
    const int q = lane >> 4, c = lane & 15;
    const int u  = (g << 4) | c;                // weight row this lane loads
    const int u4 = (g << 4) | (q << 2);         // first hidden unit this lane OWNS
    const long wgbase = (long)blockIdx.x * 64;

    // ---- stage enc (= x(0) = h(-1)) into all layer buffers, parity 1 ----
    if (tid < 512) {
        const int row = tid >> 3, k0 = (tid & 7) << 3;   // 8 floats per thread
        const int j = row >> 5, rr = row & 31;
        const float* p = enc + (wgbase + row) * ESZ + k0;
        floatx4 s0 = *(const floatx4*)p;
        floatx4 s1 = *(const floatx4*)(p + 4);
        half8 v;
        #pragma unroll
        for (int x = 0; x < 4; ++x) { v[x] = (_Float16)s0[x]; v[4 + x] = (_Float16)s1[x]; }
        #pragma unroll
        for (int ly = 0; ly < 3; ++ly)
            *(half8*)&s_hl[((ly * NT + j) * 2 + 1) * TB32 + rr * LDW + k0] = v;
    }
    if (tid < 3 * NT) s_flag[tid] = 0;

    // ---- weight fragments (A-operand) ----
    auto ldw8s = [&](const float* p, float sc) {
        floatx4 a = *(const floatx4*)p, b = *(const floatx4*)(p + 4);
        half8 v;
        #pragma unroll
        for (int x = 0; x < 4; ++x) { v[x] = (_Float16)(a[x] * sc); v[4 + x] = (_Float16)(b[x] * sc); }
        return v;
    };
    half8 fR[4], fZ[4], fNi[2], fNh[2], fO[2];
    fO[0] = fO[1] = half8{};
    if (l == 0) {
        // ---- fold W' = W_ih0 @ W_e (fp32), b' = W_ih0 @ b_e ----
        const float* wi = w_ih;
        const float* wh = w_hh;
        floatx4 aR[4], aZ[4], aN[4];
        #pragma unroll
        for (int x = 0; x < 4; ++x) { aR[x] = {0,0,0,0}; aZ[x] = {0,0,0,0}; aN[x] = {0,0,0,0}; }
        float bR = 0.f, bZ = 0.f, bN = 0.f;
        for (int k4 = 0; k4 < 64; k4 += 4) {
            floatx4 wr4 = *(const floatx4*)(wi + (u) * 64 + k4);
            floatx4 wz4 = *(const floatx4*)(wi + (64 + u) * 64 + k4);
            floatx4 wn4 = *(const floatx4*)(wi + (128 + u) * 64 + k4);
            floatx4 be4 = *(const floatx4*)(emb_b + k4);
            #pragma unroll
            for (int kk = 0; kk < 4; ++kk) {
                const float* er = emb_w + (k4 + kk) * 64;
                floatx4 e0 = *(const floatx4*)(er + q * 8);
                floatx4 e1 = *(const floatx4*)(er + q * 8 + 4);
                floatx4 e2 = *(const floatx4*)(er + 32 + q * 8);
                floatx4 e3 = *(const floatx4*)(er + 32 + q * 8 + 4);
                const float wr = wr4[kk], wz = wz4[kk], wn = wn4[kk];
                aR[0] += wr * e0; aR[1] += wr * e1; aR[2] += wr * e2; aR[3] += wr * e3;
                aZ[0] += wz * e0; aZ[1] += wz * e1; aZ[2] += wz * e2; aZ[3] += wz * e3;
                aN[0] += wn * e0; aN[1] += wn * e1; aN[2] += wn * e2; aN[3] += wn * e3;
                bR += wr * be4[kk]; bZ += wz * be4[kk]; bN += wn * be4[kk];
            }
        }
        #pragma unroll
        for (int x = 0; x < 4; ++x) {
            fR[0][x] = (_Float16)(-L2E * aR[0][x]);   fR[0][4 + x] = (_Float16)(-L2E * aR[1][x]);
            fR[1][x] = (_Float16)(-L2E * aR[2][x]);   fR[1][4 + x] = (_Float16)(-L2E * aR[3][x]);
            fZ[0][x] = (_Float16)(-L2E * aZ[0][x]);   fZ[0][4 + x] = (_Float16)(-L2E * aZ[1][x]);
            fZ[1][x] = (_Float16)(-L2E * aZ[2][x]);   fZ[1][4 + x] = (_Float16)(-L2E * aZ[3][x]);
            fNi[0][x] = (_Float16)(2*L2E * aN[0][x]); fNi[0][4 + x] = (_Float16)(2*L2E * aN[1][x]);
            fNi[1][x] = (_Float16)(2*L2E * aN[2][x]); fNi[1][4 + x] = (_Float16)(2*L2E * aN[3][x]);
        }
        fR[2]  = ldw8s(wh + (u) * 64 + q * 8, -L2E);        fR[3]  = ldw8s(wh + (u) * 64 + 32 + q * 8, -L2E);
        fZ[2]  = ldw8s(wh + (64 + u) * 64 + q * 8, -L2E);   fZ[3]  = ldw8s(wh + (64 + u) * 64 + 32 + q * 8, -L2E);
        fNh[0] = ldw8s(wh + (128 + u) * 64 + q * 8, 2*L2E); fNh[1] = ldw8s(wh + (128 + u) * 64 + 32 + q * 8, 2*L2E);
        if (q == 0) {                                // fold-bias per hidden unit u (q-invariant)
            s_btmp[u] = bR; s_btmp[64 + u] = bZ; s_btmp[128 + u] = bN;
        }
        const int oc = (c < NOUTC) ? c : 0;
        fO[0] = ldw8s(out_w + oc * 64 + q * 8, 1.f);
        fO[1] = ldw8s(out_w + oc * 64 + 32 + q * 8, 1.f);
    } else {
        const float* wi = w_ih + l * 3 * HSZ * ESZ;
        const float* wh = w_hh + l * 3 * HSZ * ESZ;
        fR[0]  = ldw8s(wi + (u) * 64 + q * 8, -L2E);        fR[1]  = ldw8s(wi + (u) * 64 + 32 + q * 8, -L2E);
        fR[2]  = ldw8s(wh + (u) * 64 + q * 8, -L2E);        fR[3]  = ldw8s(wh + (u) * 64 + 32 + q * 8, -L2E);
        fZ[0]  = ldw8s(wi + (64 + u) * 64 + q * 8, -L2E);   fZ[1]  = ldw8s(wi + (64 + u) * 64 + 32 + q * 8, -L2E);
        fZ[2]  = ldw8s(wh + (64 + u) * 64 + q * 8, -L2E);   fZ[3]  = ldw8s(wh + (64 + u) * 64 + 32 + q * 8, -L2E);
        fNi[0] = ldw8s(wi + (128 + u) * 64 + q * 8, 2*L2E); fNi[1] = ldw8s(wi + (128 + u) * 64 + 32 + q * 8, 2*L2E);
        fNh[0] = ldw8s(wh + (128 + u) * 64 + q * 8, 2*L2E); fNh[1] = ldw8s(wh + (128 + u) * 64 + 32 + q * 8, 2*L2E);
    }
    __syncthreads();                                 // staging + s_btmp + flags visible

    // ---- per-lane bias vectors (C-init), hidden units u4..u4+3 ----
    floatx4 bR4, bZ4, bNi4, bNh4;
    if (l == 0) {
        #pragma unroll
        for (int i = 0; i < 4; ++i) {
            bR4[i]  = -L2E * (s_btmp[u4 + i] + b_ih[u4 + i] + b_hh[u4 + i]);
            bZ4[i]  = -L2E * (s_btmp[64 + u4 + i] + b_ih[64 + u4 + i] + b_hh[64 + u4 + i]);
            bNi4[i] = 2.f * L2E * (s_btmp[128 + u4 + i] + b_ih[128 + u4 + i]);
            bNh4[i] = 2.f * L2E * b_hh[128 + u4 + i];
        }
    } else {
        const int b0 = l * 192;
        floatx4 bi0 = *(const floatx4*)(b_ih + b0 + u4),       bh0 = *(const floatx4*)(b_hh + b0 + u4);
        floatx4 bi1 = *(const floatx4*)(b_ih + b0 + 64 + u4),  bh1 = *(const floatx4*)(b_hh + b0 + 64 + u4);
        floatx4 bi2 = *(const floatx4*)(b_ih + b0 + 128 + u4), bh2 = *(const floatx4*)(b_hh + b0 + 128 + u4);
        #pragma unroll
        for (int i = 0; i < 4; ++i) {
            bR4[i]  = -L2E * (bi0[i] + bh0[i]);
            bZ4[i]  = -L2E * (bi1[i] + bh1[i]);
            bNi4[i] = 2.f * L2E * bi2[i];
            bNh4[i] = 2.f * L2E * bh2[i];
        }
    }
    const float ob0 = out_b[0], ob1 = out_b[1];

    // ---- fp32 h-carry in VGPRs: ca{tile}{subtile}[i] = h[u4+i][batch c] ----
    floatx4 ca00 = *(const floatx4*)(enc + (wgbase +  0 + c) * 64 + u4);
    floatx4 ca01 = *(const floatx4*)(enc + (wgbase + 16 + c) * 64 + u4);
    floatx4 ca10 = *(const floatx4*)(enc + (wgbase + 32 + c) * 64 + u4);
    floatx4 ca11 = *(const floatx4*)(enc + (wgbase + 48 + c) * 64 + u4);

    const int ar = c * LDW + (q << 3);               // act-frag offset, subtile 0
    const int fh = l * NT, fx = ((l == 0) ? 2 : (l - 1)) * NT;
    const int myj = g >> 1, mys = g & 1;             // out-proj assignment (l==0)

    auto iter = [&](const int j, floatx4& cs0, floatx4& cs1, const int t,
                    const int parh, const int parw) {
        // wait: h_l(t-1) complete (all 4 col-groups)
        { volatile const int* f = &s_flag[fh + j]; const int tg = 4 * t; while (*f < tg) {} }
        asm volatile("" ::: "memory");
        const _Float16* hb = s_hl + ((fh + j) * 2 + parh) * TB32;
        half8 ah00 = *(const half8*)(hb + ar),             ah01 = *(const half8*)(hb + ar + 32);
        half8 ah10 = *(const half8*)(hb + ar + 16 * LDW),  ah11 = *(const half8*)(hb + ar + 16 * LDW + 32);
        floatx4 accr0 = bR4, accz0 = bZ4, accnh0 = bNh4;
        floatx4 accr1 = bR4, accz1 = bZ4, accnh1 = bNh4;
        accr0  = MFMA(fR[2], ah00, accr0);   accr0  = MFMA(fR[3], ah01, accr0);
        accz0  = MFMA(fZ[2], ah00, accz0);   accz0  = MFMA(fZ[3], ah01, accz0);
        accnh0 = MFMA(fNh[0], ah00, accnh0); accnh0 = MFMA(fNh[1], ah01, accnh0);
        accr1  = MFMA(fR[2], ah10, accr1);   accr1  = MFMA(fR[3], ah11, accr1);
        accz1  = MFMA(fZ[2], ah10, accz1);   accz1  = MFMA(fZ[3], ah11, accz1);
        accnh1 = MFMA(fNh[0], ah10, accnh1); accnh1 = MFMA(fNh[1], ah11, accnh1);
        // wait: x ready (l=0: h2(t-1) gen t; l>=1: h_{l-1}(t) gen t+1)
        { volatile const int* f = &s_flag[fx + j]; const int tg = (l == 0) ? 4 * t : 4 * t + 4; while (*f < tg) {} }
        asm volatile("" ::: "memory");
        const _Float16* xb = (l == 0) ? s_hl + ((2 * NT + j) * 2 + parh) * TB32
                                      : s_hl + (((l - 1) * NT + j) * 2 + parw) * TB32;
        half8 bx00 = *(const half8*)(xb + ar),             bx01 = *(const half8*)(xb + ar + 32);
        half8 bx10 = *(const half8*)(xb + ar + 16 * LDW),  bx11 = *(const half8*)(xb + ar + 16 * LDW + 32);
        // x-side MFMAs CHAINED into the same accumulators (R10 lesson)
        accr0  = MFMA(fR[0], bx00, accr0);   accr0  = MFMA(fR[1], bx01, accr0);
        accz0  = MFMA(fZ[0], bx00, accz0);   accz0  = MFMA(fZ[1], bx01, accz0);
        floatx4 accni0 = bNi4;
        accni0 = MFMA(fNi[0], bx00, accni0); accni0 = MFMA(fNi[1], bx01, accni0);
        accr1  = MFMA(fR[0], bx10, accr1);   accr1  = MFMA(fR[1], bx11, accr1);
        accz1  = MFMA(fZ[0], bx10, accz1);   accz1  = MFMA(fZ[1], bx11, accz1);
        floatx4 accni1 = bNi4;
        accni1 = MFMA(fNi[0], bx10, accni1); accni1 = MFMA(fNi[1], bx11, accni1);
        _Float16* hw = s_hl + ((fh + j) * 2 + parw) * TB32 + c * LDW + u4;
        {   // gates subtile 0
            half4 hv4; floatx4 hnew;
            #pragma unroll
            for (int i = 0; i < 4; ++i) {
                const float r  = __builtin_amdgcn_rcpf(1.f + __builtin_amdgcn_exp2f(accr0[i]));
                const float z  = __builtin_amdgcn_rcpf(1.f + __builtin_amdgcn_exp2f(accz0[i]));
                const float a  = accni0[i] + r * accnh0[i];
                const float n  = 1.f - 2.f * __builtin_amdgcn_rcpf(1.f + __builtin_amdgcn_exp2f(a));
                const float hv = n + z * (cs0[i] - n);
                hnew[i] = hv; hv4[i] = (_Float16)hv;
            }
            *(half4*)hw = hv4;
            cs0 = hnew;
        }
        {   // gates subtile 1
            half4 hv4; floatx4 hnew;
            #pragma unroll
            for (int i = 0; i < 4; ++i) {
                const float r  = __builtin_amdgcn_rcpf(1.f + __builtin_amdgcn_exp2f(accr1[i]));
                const float z  = __builtin_amdgcn_rcpf(1.f + __builtin_amdgcn_exp2f(accz1[i]));
                const float a  = accni1[i] + r * accnh1[i];
                const float n  = 1.f - 2.f * __builtin_amdgcn_rcpf(1.f + __builtin_amdgcn_exp2f(a));
                const float hv = n + z * (cs1[i] - n);
                hnew[i] = hv; hv4[i] = (_Float16)hv;
            }
            *(half4*)(hw + 16 * LDW) = hv4;
            cs1 = hnew;
        }
        asm volatile("s_waitcnt lgkmcnt(0)" ::: "memory");   // writes visible before post
        if (lane == 0) atomicAdd(&s_flag[fh + j], 1);
        // out-proj AFTER the post; balanced: wave g serves tile g>>1, subtile g&1
        if (l == 0 && myj == j && t >= 1) {          // out(t-1) = h2(t-1) @ out_w.T + out_b
            const half8 ox0 = mys ? bx10 : bx00;
            const half8 ox1 = mys ? bx11 : bx01;
            floatx4 oa = {ob0, ob1, 0.f, 0.f};
            oa = MFMA(fO[0], ox0, oa);
            oa = MFMA(fO[1], ox1, oa);
            if (q == 0) {
                const long row = wgbase + j * 32 + mys * 16 + c;
                *(floatx2*)(out + (row * TLEN + (t - 1)) * NOUTC) = floatx2{oa[0], oa[1]};
            }
        }
    };

    for (int tt = 0; tt < TLEN; tt += 2) {           // x2 unroll: parities compile-time
        iter(0, ca00, ca01, tt,     1, 0);
        iter(1, ca10, ca11, tt,     1, 0);
        iter(0, ca00, ca01, tt + 1, 0, 1);
        iter(1, ca10, ca11, tt + 1, 0, 1);
    }

    // ---- tail: out(127) from h2(127); each L0 wave its own (tile,subtile) ----
    if (l == 0) {
        const int j = myj;
        { volatile const int* f = &s_flag[2 * NT + j]; while (*f < 4 * TLEN) {} }
        asm volatile("" ::: "memory");
        const _Float16* xb = s_hl + ((2 * NT + j) * 2 + 1) * TB32 + mys * 16 * LDW;  // parity 127&1=1
        half8 bx0 = *(const half8*)(xb + ar), bx1 = *(const half8*)(xb + ar + 32);
        floatx4 oa = {ob0, ob1, 0.f, 0.f};
        oa = MFMA(fO[0], bx0, oa);
        oa = MFMA(fO[1], bx1, oa);
        if (q == 0) {
            const long row = wgbase + j * 32 + mys * 16 + c;
            *(floatx2*)(out + (row * TLEN + 127) * NOUTC) = floatx2{oa[0], oa[1]};
        }
    }
}

extern "C" void kernel_launch(void* const* d_in, const int* in_sizes, int n_in,
                              void* d_out, int out_size, void* d_ws, size_t ws_size,
                              hipStream_t stream) {
    (void)in_sizes; (void)n_in; (void)d_ws; (void)ws_size; (void)out_size;
    const int grid = 16384 / 64;   // 256 workgroups, 1 per CU
    gru_pipe<<<grid, 768, 0, stream>>>(
        (const float*)d_in[0],  // agentFutureTrajEnc
        (const float*)d_in[1],  // emb_w
        (const float*)d_in[2],  // emb_b
        (const float*)d_in[3],  // w_ih
        (const float*)d_in[4],  // w_hh
        (const float*)d_in[5],  // b_ih
        (const float*)d_in[6],  // b_hh
        (const float*)d_in[7],  // out_w
        (const float*)d_in[8],  // out_b
        (float*)d_out);
}